// Round 6
// baseline (552.682 us; speedup 1.0000x reference)
//
#include <hip/hip_runtime.h>
#include <math.h>

#define NUM_ENT 100000
#define NUM_EDGES 200000
#define DIM 768
#define BM 64
#define KSTEPS 24
#define NC 16
#define DCH 48

typedef float f32x4 __attribute__((ext_vector_type(4)));
typedef __bf16 bf16x8 __attribute__((ext_vector_type(8)));

// ---- ws layout (float indices) ----
#define WS_Y1    0        // 3*768
#define WS_CQ    2304     // 3*768
#define WS_HA    4704     // 3 hop_attn
#define WS_HOP1  4736     // 256
#define WS_CTX   4992     // 3*768
#define WS_B     7424     // rw1 bf16 frag-ordered: 384 frags * 1KB = 49152 floats
#define WS_DPROB 302336   // 3*200000 (also transient home of P1/P2 partials)
#define WS_P1    302336   // 48*768
#define WS_P1H   339200   // 16*256
#define WS_P2    343296   // 48*768
#define WS_E     902336   // 4*100000 (slot 0 unused; e1..e3 raw sums)

__device__ __forceinline__ unsigned short f2bf(float f) {
    unsigned int x = __builtin_bit_cast(unsigned int, f);
    x = x + 0x7fffu + ((x >> 16) & 1u);   // RTNE
    return (unsigned short)(x >> 16);
}

// A&S 7.1.26 erf approx, |eps| <= 1.5e-7
__device__ __forceinline__ float gelu_f(float x) {
    float z = 0.70710678118654752f * x;
    float s = fabsf(z);
    float t = 1.f / (1.f + 0.3275911f * s);
    float p = t * (0.254829592f + t * (-0.284496736f + t * (1.421413741f +
              t * (-1.453152027f + t * 1.061405429f))));
    float e = __expf(-s * s);
    float erfa = copysignf(1.f - p * e, z);
    return 0.5f * x * (1.f + erfa);
}

// K1a: d-split partials for step layer-1 (48 blocks) and hop layer-1 (16 blocks)
__global__ void k1a(const float* __restrict__ q, const float* __restrict__ sw1,
                    const float* __restrict__ hw1, float* __restrict__ ws) {
    int b = blockIdx.x, tid = threadIdx.x;
    if (b < 48) {
        int t = b >> 4, c = b & 15;
        const float* w = sw1 + (size_t)t * DIM * DIM + (size_t)c * DCH * DIM;
        float a0 = 0.f, a1 = 0.f, a2 = 0.f;
        for (int d = 0; d < DCH; ++d) {
            float qv = q[c * DCH + d];
            const float* wr = w + (size_t)d * DIM;
            a0 += qv * wr[tid]; a1 += qv * wr[tid + 256]; a2 += qv * wr[tid + 512];
        }
        float* p = ws + WS_P1 + (size_t)b * DIM;
        p[tid] = a0; p[tid + 256] = a1; p[tid + 512] = a2;
    } else {
        int c = b - 48;
        const float* w = hw1 + (size_t)c * DCH * 256;
        float a0 = 0.f;
        for (int d = 0; d < DCH; ++d) a0 += q[c * DCH + d] * w[(size_t)d * 256 + tid];
        ws[WS_P1H + c * 256 + tid] = a0;
    }
}

// K1b: reduce partials + bias + gelu -> y1, hop1
__global__ void k1b(const float* __restrict__ sb1, const float* __restrict__ hb1,
                    float* __restrict__ ws) {
    int o = blockIdx.x * 256 + threadIdx.x;
    if (o < 2304) {
        int t = o / DIM, j = o % DIM;
        float s = sb1[o];
        for (int c = 0; c < NC; ++c) s += ws[WS_P1 + (size_t)(t * 16 + c) * DIM + j];
        ws[WS_Y1 + o] = gelu_f(s);
    } else if (o < 2560) {
        int j = o - 2304;
        float s = hb1[j];
        for (int c = 0; c < NC; ++c) s += ws[WS_P1H + c * 256 + j];
        ws[WS_HOP1 + j] = gelu_f(s);
    }
}

// K2a: d-split partials for step layer-2
__global__ void k2a(const float* __restrict__ sw2, float* __restrict__ ws) {
    int b = blockIdx.x, tid = threadIdx.x;
    int t = b >> 4, c = b & 15;
    const float* w = sw2 + (size_t)t * DIM * DIM + (size_t)c * DCH * DIM;
    const float* y = ws + WS_Y1 + t * DIM + c * DCH;
    float a0 = 0.f, a1 = 0.f, a2 = 0.f;
    for (int d = 0; d < DCH; ++d) {
        float yv = y[d];
        const float* wr = w + (size_t)d * DIM;
        a0 += yv * wr[tid]; a1 += yv * wr[tid + 256]; a2 += yv * wr[tid + 512];
    }
    float* p = ws + WS_P2 + (size_t)b * DIM;
    p[tid] = a0; p[tid + 256] = a1; p[tid + 512] = a2;
}

// K2b: reduce -> cq
__global__ void k2b(const float* __restrict__ sb2, float* __restrict__ ws) {
    int o = blockIdx.x * 256 + threadIdx.x;   // 0..2303
    int t = o / DIM, j = o % DIM;
    float s = sb2[o];
    for (int c = 0; c < NC; ++c) s += ws[WS_P2 + (size_t)(t * 16 + c) * DIM + j];
    ws[WS_CQ + o] = s;
}

// K345 (single block, 1024 thr): q_logits -> softmax -> ctx; hop_attn
__global__ void k345(const float* __restrict__ qwh, const float* __restrict__ hw2,
                     const float* __restrict__ hb2, float* __restrict__ ws) {
    __shared__ float qlog[96];
    int tid = threadIdx.x;
    int w = tid >> 6, lane = tid & 63;
    for (int s = 0; s < 6; ++s) {
        int p = w * 6 + s;
        int t = p >> 5, l = p & 31;
        const float* c = ws + WS_CQ + t * DIM;
        const float* qw = qwh + l * DIM;
        float acc = 0.f;
        for (int i = lane; i < DIM; i += 64) acc += c[i] * qw[i];
        for (int m = 32; m; m >>= 1) acc += __shfl_xor(acc, m);
        if (lane == 0) qlog[p] = acc;
    }
    __syncthreads();
    if (tid < 64) {
        for (int t = 0; t < 3; ++t) {
            float v = (lane < 32) ? qlog[t * 32 + lane] : -1e30f;
            float mx = v;
            for (int m = 1; m < 32; m <<= 1) mx = fmaxf(mx, __shfl_xor(mx, m, 32));
            float e = (lane < 32) ? __expf(v - mx) : 0.f;
            float s = e;
            for (int m = 1; m < 32; m <<= 1) s += __shfl_xor(s, m, 32);
            if (lane < 32) qlog[t * 32 + lane] = e / s;
        }
        float lg = 0.f;
        if (lane < 3) {
            for (int s = 0; s < 256; ++s) lg += ws[WS_HOP1 + s] * hw2[s * 3 + lane];
            lg += hb2[lane];
        }
        float l0 = __shfl(lg, 0), l1 = __shfl(lg, 1), l2 = __shfl(lg, 2);
        if (lane == 0) {
            float mx = fmaxf(l0, fmaxf(l1, l2));
            float e0 = __expf(l0 - mx), e1 = __expf(l1 - mx), e2 = __expf(l2 - mx);
            float s = e0 + e1 + e2;
            ws[WS_HA + 0] = e0 / s; ws[WS_HA + 1] = e1 / s; ws[WS_HA + 2] = e2 / s;
        }
    }
    __syncthreads();
    for (int o = tid; o < 2304; o += 1024) {
        int t = o / DIM, d = o % DIM;
        float acc = ws[WS_CQ + o];
        const float* qd = qlog + t * 32;
        for (int l = 0; l < 32; ++l) acc += qd[l] * qwh[l * DIM + d];
        ws[WS_CTX + o] = acc;
    }
}

// K6: rw1 -> bf16 frag order (NO ctx scaling). frag f = ks*16+cf (384 frags).
// lane holds k = ks*32+(lane>>4)*8+j, col = cf*16+(lane&15)
__global__ void k6_bmat(const float* __restrict__ rw1, float* __restrict__ ws) {
    int g = blockIdx.x * 256 + threadIdx.x;   // 0..24575
    int lane = g & 63, f = g >> 6;            // f 0..383
    int ks = f >> 4, cf = f & 15;
    int k0 = ks * 32 + (lane >> 4) * 8;
    int col = cf * 16 + (lane & 15);
    union { unsigned short u[8]; bf16x8 v; } pk;
    #pragma unroll
    for (int j = 0; j < 8; ++j)
        pk.u[j] = f2bf(rw1[(size_t)(k0 + j) * 256 + col]);
    *(bf16x8*)((unsigned short*)(ws + WS_B) + (size_t)g * 8) = pk.v;
}

// one kstep of this wave: unpack raw A frags, scale by ctx_t, 24 MFMAs
#define KSTEP(KS, B0, B1, B2, B3)                                                   \
  {                                                                                  \
    const unsigned short* ab = aLds + ((size_t)((KS) * 4 + rh * 2)) * 512 + lane * 8;\
    bf16x8 a0r = *(const bf16x8*)ab;                                                 \
    bf16x8 a1r = *(const bf16x8*)(ab + 512);                                         \
    const float* cp = ctxL + (KS) * 32 + khi;                                        \
    float a0f[8], a1f[8];                                                            \
    _Pragma("unroll")                                                                \
    for (int p = 0; p < 4; ++p) {                                                    \
      unsigned int r0 = ((const unsigned int*)&a0r)[p];                              \
      unsigned int r1 = ((const unsigned int*)&a1r)[p];                              \
      a0f[2*p]   = __builtin_bit_cast(float, r0 << 16);                              \
      a0f[2*p+1] = __builtin_bit_cast(float, r0 & 0xffff0000u);                      \
      a1f[2*p]   = __builtin_bit_cast(float, r1 << 16);                              \
      a1f[2*p+1] = __builtin_bit_cast(float, r1 & 0xffff0000u);                      \
    }                                                                                \
    _Pragma("unroll")                                                                \
    for (int t = 0; t < 3; ++t) {                                                    \
      float4 cA = *(const float4*)(cp + t * DIM);                                    \
      float4 cB2 = *(const float4*)(cp + t * DIM + 4);                               \
      float cc[8] = {cA.x, cA.y, cA.z, cA.w, cB2.x, cB2.y, cB2.z, cB2.w};            \
      bf16x8 s0, s1;                                                                 \
      _Pragma("unroll")                                                              \
      for (int p = 0; p < 4; ++p) {                                                  \
        unsigned int w0, w1;                                                         \
        asm("v_cvt_pk_bf16_f32 %0, %1, %2" : "=v"(w0)                                \
            : "v"(a0f[2*p] * cc[2*p]), "v"(a0f[2*p+1] * cc[2*p+1]));                 \
        asm("v_cvt_pk_bf16_f32 %0, %1, %2" : "=v"(w1)                                \
            : "v"(a1f[2*p] * cc[2*p]), "v"(a1f[2*p+1] * cc[2*p+1]));                 \
        ((unsigned int*)&s0)[p] = w0;                                                \
        ((unsigned int*)&s1)[p] = w1;                                                \
      }                                                                              \
      acc[t][0][0] = __builtin_amdgcn_mfma_f32_16x16x32_bf16(s0, B0, acc[t][0][0], 0,0,0); \
      acc[t][0][1] = __builtin_amdgcn_mfma_f32_16x16x32_bf16(s0, B1, acc[t][0][1], 0,0,0); \
      acc[t][0][2] = __builtin_amdgcn_mfma_f32_16x16x32_bf16(s0, B2, acc[t][0][2], 0,0,0); \
      acc[t][0][3] = __builtin_amdgcn_mfma_f32_16x16x32_bf16(s0, B3, acc[t][0][3], 0,0,0); \
      acc[t][1][0] = __builtin_amdgcn_mfma_f32_16x16x32_bf16(s1, B0, acc[t][1][0], 0,0,0); \
      acc[t][1][1] = __builtin_amdgcn_mfma_f32_16x16x32_bf16(s1, B1, acc[t][1][1], 0,0,0); \
      acc[t][1][2] = __builtin_amdgcn_mfma_f32_16x16x32_bf16(s1, B2, acc[t][1][2], 0,0,0); \
      acc[t][1][3] = __builtin_amdgcn_mfma_f32_16x16x32_bf16(s1, B3, acc[t][1][3], 0,0,0); \
    }                                                                                \
  }

// K7: barrier-free K-loop GEMM, B = rw1 (shared across t), ctx folded into A
// in registers. BM=64 rows, 256 cols, 3 t's in acc. 512 thr = 8 waves
// (rh 0..1 rowhalf x cg 0..3 colgroup); wave tile = 32 rows x 64 cols x 3t
// (acc 96 f32/lane). B frag bytes per CU per kstep: 32KB vs 48KB before, and
// 24 MFMA per 4KB of B vs 16 -> TCP load ~53% instead of ~95%.
// LDS: A raw bf16 96KB @0, ctx f32 9KB @98304, part 3KB @107520 (110592 B)
__global__ __launch_bounds__(512, 2)
void k7_gemm(const float* __restrict__ desc, const float* __restrict__ rb1,
             const float* __restrict__ rw2, const float* __restrict__ rb2,
             float* __restrict__ ws) {
    extern __shared__ char lds[];
    unsigned short* aLds = (unsigned short*)lds;        // 96 frags * 512 ushort
    float* ctxL = (float*)(lds + 98304);                // 3*768 f32
    float* part = (float*)(lds + 107520);               // 4cg * 3t * 64 rows

    const unsigned short* bmat = (const unsigned short*)(ws + WS_B);
    const float* ctxg = ws + WS_CTX;
    float* dprob = ws + WS_DPROB;
    int tid = threadIdx.x, blk = blockIdx.x;
    int wid = tid >> 6, lane = tid & 63;
    int rh = wid >> 2, cg = wid & 3;
    int khi = (lane >> 4) * 8;

    // ---- B(0) prefetch into registers (completes while A stages) ----
    const unsigned short* bp = bmat + ((size_t)(cg * 4) << 9) + lane * 8;
    bf16x8 b0_0 = *(const bf16x8*)(bp);
    bf16x8 b0_1 = *(const bf16x8*)(bp + 512);
    bf16x8 b0_2 = *(const bf16x8*)(bp + 1024);
    bf16x8 b0_3 = *(const bf16x8*)(bp + 1536);
    bp += 16 * 512;

    // ---- one-time A stage: f32 -> bf16 raw, MFMA-fragment order ----
    #pragma unroll
    for (int i = 0; i < 12; ++i) {
        int gf = i * 512 + tid;            // 0..6143 (96 frags x 64 lanes)
        int l = gf & 63, f = gf >> 6;      // f = ks*4 + rf
        int ks = f >> 2, rf = f & 3;
        int row = rf * 16 + (l & 15);
        int kb = ks * 32 + (l >> 4) * 8;
        const float* src = desc + (size_t)(blk * BM + row) * DIM + kb;
        float4 v0 = *(const float4*)src;
        float4 v1 = *(const float4*)(src + 4);
        bf16x8 pk;
        pk[0] = (__bf16)v0.x; pk[1] = (__bf16)v0.y; pk[2] = (__bf16)v0.z; pk[3] = (__bf16)v0.w;
        pk[4] = (__bf16)v1.x; pk[5] = (__bf16)v1.y; pk[6] = (__bf16)v1.z; pk[7] = (__bf16)v1.w;
        *(bf16x8*)(aLds + (size_t)f * 512 + l * 8) = pk;
    }
    // ctx table
    for (int o = tid; o < 2304; o += 512) ctxL[o] = ctxg[o];
    __syncthreads();

    f32x4 acc[3][2][4];
    #pragma unroll
    for (int t = 0; t < 3; ++t)
        #pragma unroll
        for (int rf = 0; rf < 2; ++rf)
            #pragma unroll
            for (int i = 0; i < 4; ++i) acc[t][rf][i] = f32x4{0.f, 0.f, 0.f, 0.f};

    bf16x8 b1_0, b1_1, b1_2, b1_3;

    #pragma unroll 1
    for (int ks = 0; ks < KSTEPS; ks += 2) {
        b1_0 = *(const bf16x8*)(bp);
        b1_1 = *(const bf16x8*)(bp + 512);
        b1_2 = *(const bf16x8*)(bp + 1024);
        b1_3 = *(const bf16x8*)(bp + 1536);
        bp += 16 * 512;
        KSTEP(ks, b0_0, b0_1, b0_2, b0_3)
        if (ks + 2 < KSTEPS) {
            b0_0 = *(const bf16x8*)(bp);
            b0_1 = *(const bf16x8*)(bp + 512);
            b0_2 = *(const bf16x8*)(bp + 1024);
            b0_3 = *(const bf16x8*)(bp + 1536);
            bp += 16 * 512;
        }
        KSTEP(ks + 1, b1_0, b1_1, b1_2, b1_3)
    }

    // epilogue: per-row sum over this wave's 64 cols of gelu(h+b1)*w2, per t
    int col16 = lane & 15, quart = lane >> 4;
    float b1v[4], w2v[4];
    #pragma unroll
    for (int i = 0; i < 4; ++i) {
        int c = cg * 64 + i * 16 + col16;
        b1v[i] = rb1[c]; w2v[i] = rw2[c];
    }
    #pragma unroll
    for (int t = 0; t < 3; ++t)
        #pragma unroll
        for (int rf = 0; rf < 2; ++rf)
            #pragma unroll
            for (int r = 0; r < 4; ++r) {
                float s = 0.f;
                #pragma unroll
                for (int i = 0; i < 4; ++i)
                    s += gelu_f(acc[t][rf][i][r] + b1v[i]) * w2v[i];
                #pragma unroll
                for (int m = 1; m < 16; m <<= 1) s += __shfl_xor(s, m);
                if (col16 == 0)
                    part[(cg * 3 + t) * 64 + rh * 32 + rf * 16 + quart * 4 + r] = s;
            }
    __syncthreads();
    if (tid < 192) {
        int tt = tid >> 6, row = tid & 63;
        float v = part[(0 * 3 + tt) * 64 + row] + part[(1 * 3 + tt) * 64 + row]
                + part[(2 * 3 + tt) * 64 + row] + part[(3 * 3 + tt) * 64 + row] + rb2[0];
        float p = 1.f / (1.f + __expf(-v));
        dprob[(size_t)tt * NUM_EDGES + blk * BM + row] = p;
    }
}

// Kzero: zero raw accumulators e1..e3
__global__ void kzero(float* __restrict__ ws) {
    int i = blockIdx.x * 256 + threadIdx.x;
    if (i < 3 * NUM_ENT) ws[WS_E + NUM_ENT + i] = 0.f;
}

// K9: scatter step t: e_{t+1}[obj] += norm(e_t)[sub] * dprob[t][e]
__global__ void k9_scatter(const int* __restrict__ kb, const int* __restrict__ topics,
                           float* __restrict__ ws, int t) {
    int e = blockIdx.x * 256 + threadIdx.x;
    if (e >= NUM_EDGES) return;
    int sub = kb[2 * e], obj = kb[2 * e + 1];
    float g;
    if (t == 0) {
        g = (sub == topics[0] || sub == topics[1] || sub == topics[2] || sub == topics[3]) ? 1.f : 0.f;
    } else {
        float v = ws[WS_E + (size_t)t * NUM_ENT + sub];
        g = v / fmaxf(v, 1.f);
    }
    float p = g * ws[WS_DPROB + (size_t)t * NUM_EDGES + e];
    if (p != 0.f) atomicAdd(&ws[WS_E + (size_t)(t + 1) * NUM_ENT + obj], p);
}

// Kout: out[i] = sum_t hop_attn[t] * norm(e_{t+1})[i]
__global__ void kout(const float* __restrict__ ws, float* __restrict__ out) {
    int i = blockIdx.x * 256 + threadIdx.x;
    if (i >= NUM_ENT) return;
    float v1 = ws[WS_E + 1 * NUM_ENT + i]; v1 /= fmaxf(v1, 1.f);
    float v2 = ws[WS_E + 2 * NUM_ENT + i]; v2 /= fmaxf(v2, 1.f);
    float v3 = ws[WS_E + 3 * NUM_ENT + i]; v3 /= fmaxf(v3, 1.f);
    out[i] = ws[WS_HA + 0] * v1 + ws[WS_HA + 1] * v2 + ws[WS_HA + 2] * v3;
}

extern "C" void kernel_launch(void* const* d_in, const int* in_sizes, int n_in,
                              void* d_out, int out_size, void* d_ws, size_t ws_size,
                              hipStream_t stream) {
    const float* q_emb   = (const float*)d_in[0];
    const float* qwh     = (const float*)d_in[1];
    const float* desc    = (const float*)d_in[2];
    const float* sw1     = (const float*)d_in[3];
    const float* sb1     = (const float*)d_in[4];
    const float* sw2     = (const float*)d_in[5];
    const float* sb2     = (const float*)d_in[6];
    const float* rw1     = (const float*)d_in[7];
    const float* rb1     = (const float*)d_in[8];
    const float* rw2     = (const float*)d_in[9];
    const float* rb2     = (const float*)d_in[10];
    const float* hw1     = (const float*)d_in[11];
    const float* hb1     = (const float*)d_in[12];
    const float* hw2     = (const float*)d_in[13];
    const float* hb2     = (const float*)d_in[14];
    const int*   kb      = (const int*)d_in[15];
    const int*   topics  = (const int*)d_in[16];
    float* ws  = (float*)d_ws;
    float* out = (float*)d_out;

    int nblk7 = NUM_EDGES / BM;   // 3125, exact

    kzero<<<(3 * NUM_ENT + 255) / 256, 256, 0, stream>>>(ws);
    k1a<<<64, 256, 0, stream>>>(q_emb, sw1, hw1, ws);
    k1b<<<10, 256, 0, stream>>>(sb1, hb1, ws);
    k2a<<<48, 256, 0, stream>>>(sw2, ws);
    k2b<<<9, 256, 0, stream>>>(sb2, ws);
    k345<<<1, 1024, 0, stream>>>(qwh, hw2, hb2, ws);
    k6_bmat<<<96, 256, 0, stream>>>(rw1, ws);
    k7_gemm<<<nblk7, 512, 110592, stream>>>(desc, rb1, rw2, rb2, ws);
    for (int t = 0; t < 3; ++t)
        k9_scatter<<<(NUM_EDGES + 255) / 256, 256, 0, stream>>>(kb, topics, ws, t);
    kout<<<(NUM_ENT + 255) / 256, 256, 0, stream>>>(ws, out);
}

// Round 7
// 474.956 us; speedup vs baseline: 1.1636x; 1.1636x over previous
//
#include <hip/hip_runtime.h>
#include <math.h>

#define NUM_ENT 100000
#define NUM_EDGES 200000
#define DIM 768
#define BM 64
#define KSTEPS 24
#define NC 16
#define DCH 48

typedef float f32x4 __attribute__((ext_vector_type(4)));
typedef __bf16 bf16x8 __attribute__((ext_vector_type(8)));

// ---- ws layout (float indices) ----
#define WS_Y1    0        // 3*768
#define WS_CQ    2304     // 3*768
#define WS_HA    4704     // 3 hop_attn
#define WS_HOP1  4736     // 256
#define WS_CTX   4992     // 3*768
#define WS_B     7424     // bf16 frag-ordered: 24 chunks * 48 frags * 1KB
#define WS_DPROB 302336   // 3*200000 (also transient home of P1/P2 partials)
#define WS_P1    302336   // 48*768
#define WS_P1H   339200   // 16*256
#define WS_P2    343296   // 48*768
#define WS_E     902336   // 4*100000 (slot 0 unused; e1..e3 raw sums)

__device__ __forceinline__ unsigned short f2bf(float f) {
    unsigned int x = __builtin_bit_cast(unsigned int, f);
    x = x + 0x7fffu + ((x >> 16) & 1u);   // RTNE
    return (unsigned short)(x >> 16);
}

// A&S 7.1.26 erf approx, |eps| <= 1.5e-7
__device__ __forceinline__ float gelu_f(float x) {
    float z = 0.70710678118654752f * x;
    float s = fabsf(z);
    float t = 1.f / (1.f + 0.3275911f * s);
    float p = t * (0.254829592f + t * (-0.284496736f + t * (1.421413741f +
              t * (-1.453152027f + t * 1.061405429f))));
    float e = __expf(-s * s);
    float erfa = copysignf(1.f - p * e, z);
    return 0.5f * x * (1.f + erfa);
}

// K1a: d-split partials for step layer-1 (48 blocks) and hop layer-1 (16 blocks)
__global__ void k1a(const float* __restrict__ q, const float* __restrict__ sw1,
                    const float* __restrict__ hw1, float* __restrict__ ws) {
    int b = blockIdx.x, tid = threadIdx.x;
    if (b < 48) {
        int t = b >> 4, c = b & 15;
        const float* w = sw1 + (size_t)t * DIM * DIM + (size_t)c * DCH * DIM;
        float a0 = 0.f, a1 = 0.f, a2 = 0.f;
        for (int d = 0; d < DCH; ++d) {
            float qv = q[c * DCH + d];
            const float* wr = w + (size_t)d * DIM;
            a0 += qv * wr[tid]; a1 += qv * wr[tid + 256]; a2 += qv * wr[tid + 512];
        }
        float* p = ws + WS_P1 + (size_t)b * DIM;
        p[tid] = a0; p[tid + 256] = a1; p[tid + 512] = a2;
    } else {
        int c = b - 48;
        const float* w = hw1 + (size_t)c * DCH * 256;
        float a0 = 0.f;
        for (int d = 0; d < DCH; ++d) a0 += q[c * DCH + d] * w[(size_t)d * 256 + tid];
        ws[WS_P1H + c * 256 + tid] = a0;
    }
}

// K1b: reduce partials + bias + gelu -> y1, hop1
__global__ void k1b(const float* __restrict__ sb1, const float* __restrict__ hb1,
                    float* __restrict__ ws) {
    int o = blockIdx.x * 256 + threadIdx.x;
    if (o < 2304) {
        int t = o / DIM, j = o % DIM;
        float s = sb1[o];
        for (int c = 0; c < NC; ++c) s += ws[WS_P1 + (size_t)(t * 16 + c) * DIM + j];
        ws[WS_Y1 + o] = gelu_f(s);
    } else if (o < 2560) {
        int j = o - 2304;
        float s = hb1[j];
        for (int c = 0; c < NC; ++c) s += ws[WS_P1H + c * 256 + j];
        ws[WS_HOP1 + j] = gelu_f(s);
    }
}

// K2a: d-split partials for step layer-2
__global__ void k2a(const float* __restrict__ sw2, float* __restrict__ ws) {
    int b = blockIdx.x, tid = threadIdx.x;
    int t = b >> 4, c = b & 15;
    const float* w = sw2 + (size_t)t * DIM * DIM + (size_t)c * DCH * DIM;
    const float* y = ws + WS_Y1 + t * DIM + c * DCH;
    float a0 = 0.f, a1 = 0.f, a2 = 0.f;
    for (int d = 0; d < DCH; ++d) {
        float yv = y[d];
        const float* wr = w + (size_t)d * DIM;
        a0 += yv * wr[tid]; a1 += yv * wr[tid + 256]; a2 += yv * wr[tid + 512];
    }
    float* p = ws + WS_P2 + (size_t)b * DIM;
    p[tid] = a0; p[tid + 256] = a1; p[tid + 512] = a2;
}

// K2b: reduce -> cq
__global__ void k2b(const float* __restrict__ sb2, float* __restrict__ ws) {
    int o = blockIdx.x * 256 + threadIdx.x;   // 0..2303
    int t = o / DIM, j = o % DIM;
    float s = sb2[o];
    for (int c = 0; c < NC; ++c) s += ws[WS_P2 + (size_t)(t * 16 + c) * DIM + j];
    ws[WS_CQ + o] = s;
}

// K345 (single block, 1024 thr): q_logits -> softmax -> ctx; hop_attn
__global__ void k345(const float* __restrict__ qwh, const float* __restrict__ hw2,
                     const float* __restrict__ hb2, float* __restrict__ ws) {
    __shared__ float qlog[96];
    int tid = threadIdx.x;
    int w = tid >> 6, lane = tid & 63;
    for (int s = 0; s < 6; ++s) {
        int p = w * 6 + s;
        int t = p >> 5, l = p & 31;
        const float* c = ws + WS_CQ + t * DIM;
        const float* qw = qwh + l * DIM;
        float acc = 0.f;
        for (int i = lane; i < DIM; i += 64) acc += c[i] * qw[i];
        for (int m = 32; m; m >>= 1) acc += __shfl_xor(acc, m);
        if (lane == 0) qlog[p] = acc;
    }
    __syncthreads();
    if (tid < 64) {
        for (int t = 0; t < 3; ++t) {
            float v = (lane < 32) ? qlog[t * 32 + lane] : -1e30f;
            float mx = v;
            for (int m = 1; m < 32; m <<= 1) mx = fmaxf(mx, __shfl_xor(mx, m, 32));
            float e = (lane < 32) ? __expf(v - mx) : 0.f;
            float s = e;
            for (int m = 1; m < 32; m <<= 1) s += __shfl_xor(s, m, 32);
            if (lane < 32) qlog[t * 32 + lane] = e / s;
        }
        float lg = 0.f;
        if (lane < 3) {
            for (int s = 0; s < 256; ++s) lg += ws[WS_HOP1 + s] * hw2[s * 3 + lane];
            lg += hb2[lane];
        }
        float l0 = __shfl(lg, 0), l1 = __shfl(lg, 1), l2 = __shfl(lg, 2);
        if (lane == 0) {
            float mx = fmaxf(l0, fmaxf(l1, l2));
            float e0 = __expf(l0 - mx), e1 = __expf(l1 - mx), e2 = __expf(l2 - mx);
            float s = e0 + e1 + e2;
            ws[WS_HA + 0] = e0 / s; ws[WS_HA + 1] = e1 / s; ws[WS_HA + 2] = e2 / s;
        }
    }
    __syncthreads();
    for (int o = tid; o < 2304; o += 1024) {
        int t = o / DIM, d = o % DIM;
        float acc = ws[WS_CQ + o];
        const float* qd = qlog + t * 32;
        for (int l = 0; l < 32; ++l) acc += qd[l] * qwh[l * DIM + d];
        ws[WS_CTX + o] = acc;
    }
}

// K6: B bf16, K-chunk-major frag order: chunk ks (0..23) holds 48 frags (t*16+cf)
__global__ void k6_bmat(const float* __restrict__ rw1, float* __restrict__ ws) {
    int g = blockIdx.x * 256 + threadIdx.x;   // 0..73727
    int lane = g & 63, f = g >> 6;            // f 0..1151
    int ks = f / 48, r = f % 48;
    int t = r >> 4, cf = r & 15;
    int k0 = ks * 32 + (lane >> 4) * 8;
    int col = cf * 16 + (lane & 15);
    const float* ctx = ws + WS_CTX + t * DIM;
    union { unsigned short u[8]; bf16x8 v; } pk;
    #pragma unroll
    for (int j = 0; j < 8; ++j) {
        float v = ctx[k0 + j] * rw1[(size_t)(k0 + j) * 256 + col];
        pk.u[j] = f2bf(v);
    }
    *(bf16x8*)((unsigned short*)(ws + WS_B) + (size_t)g * 8) = pk.v;
}

#define MFMA4(A, B0, B1, B2, B3, RF)                                               \
    acc[RF][0] = __builtin_amdgcn_mfma_f32_16x16x32_bf16(A, B0, acc[RF][0], 0,0,0); \
    acc[RF][1] = __builtin_amdgcn_mfma_f32_16x16x32_bf16(A, B1, acc[RF][1], 0,0,0); \
    acc[RF][2] = __builtin_amdgcn_mfma_f32_16x16x32_bf16(A, B2, acc[RF][2], 0,0,0); \
    acc[RF][3] = __builtin_amdgcn_mfma_f32_16x16x32_bf16(A, B3, acc[RF][3], 0,0,0);

#define MSTEP(KS, B0, B1, B2, B3) {                                                \
    const unsigned short* ab = ab0 + (size_t)(KS) * 2048;                          \
    bf16x8 a;                                                                      \
    a = *(const bf16x8*)(ab);          MFMA4(a, B0, B1, B2, B3, 0)                 \
    a = *(const bf16x8*)(ab + 512);    MFMA4(a, B0, B1, B2, B3, 1)                 \
    a = *(const bf16x8*)(ab + 1024);   MFMA4(a, B0, B1, B2, B3, 2)                 \
    a = *(const bf16x8*)(ab + 1536);   MFMA4(a, B0, B1, B2, B3, 3)                 \
}

#define LOADB(N0, N1, N2, N3, KS) {                                                \
    const unsigned short* p = bp0 + (size_t)(KS) * 24576;                          \
    N0 = *(const bf16x8*)(p);        N1 = *(const bf16x8*)(p + 512);               \
    N2 = *(const bf16x8*)(p + 1024); N3 = *(const bf16x8*)(p + 1536);              \
}

// K7: barrier-free K-loop GEMM + fused epilogue -> dprob[t][edge]
// BM=64 rows, BN=768 (3t x 256), BK=32, 768 thr = 12 waves (wid = t*4+cg).
// A: staged bf16 in LDS ONCE per block (96 KB), read-only in the K-loop.
// B: per-wave direct global->VGPR, FOUR named buffer sets reloaded 4 ksteps
//    ahead (depth ~3.7 ksteps) to cover L2 load-to-use latency under full-chip
//    contention -- r5's depth-1 left ~1000 cyc/kstep exposed. Compiler inserts
//    the counted vmcnt per buffer group. No barriers in the K-loop.
// LDS: A 98304 B @0, part 12x64 f32 @98304 (101376 B total)
__global__ __launch_bounds__(768, 3)
void k7_gemm(const float* __restrict__ desc, const float* __restrict__ rb1,
             const float* __restrict__ rw2, const float* __restrict__ rb2,
             float* __restrict__ ws) {
    extern __shared__ char lds[];
    unsigned short* aLds = (unsigned short*)lds;   // 96 frags * 512 ushort
    float* part = (float*)(lds + 98304);           // 12 * 64

    const unsigned short* bmat = (const unsigned short*)(ws + WS_B);
    float* dprob = ws + WS_DPROB;
    int tid = threadIdx.x, blk = blockIdx.x;
    int wid = tid >> 6, lane = tid & 63;
    int t = wid >> 2, cg = wid & 3;
    int fbase = (t << 4) + (cg << 2);   // this wave's 4 B-frags per kstep

    const unsigned short* bp0 = bmat + ((size_t)fbase << 9) + lane * 8;

    // ---- B(0..3) prefetch into registers (completes while A stages) ----
    bf16x8 bA0, bA1, bA2, bA3, bB0, bB1, bB2, bB3;
    bf16x8 bC0, bC1, bC2, bC3, bD0, bD1, bD2, bD3;
    LOADB(bA0, bA1, bA2, bA3, 0)
    LOADB(bB0, bB1, bB2, bB3, 1)
    LOADB(bC0, bC1, bC2, bC3, 2)
    LOADB(bD0, bD1, bD2, bD3, 3)

    // ---- one-time A stage: f32 -> bf16, MFMA-fragment order ----
    #pragma unroll
    for (int i = 0; i < 8; ++i) {
        int gf = i * 768 + tid;            // 0..6143 slots (96 frags x 64 lanes)
        int l = gf & 63, f = gf >> 6;      // f = ks*4 + rf
        int ks = f >> 2, rf = f & 3;
        int row = rf * 16 + (l & 15);
        int kb = ks * 32 + (l >> 4) * 8;
        const float* src = desc + (size_t)(blk * BM + row) * DIM + kb;
        float4 v0 = *(const float4*)src;
        float4 v1 = *(const float4*)(src + 4);
        bf16x8 pk;
        pk[0] = (__bf16)v0.x; pk[1] = (__bf16)v0.y; pk[2] = (__bf16)v0.z; pk[3] = (__bf16)v0.w;
        pk[4] = (__bf16)v1.x; pk[5] = (__bf16)v1.y; pk[6] = (__bf16)v1.z; pk[7] = (__bf16)v1.w;
        *(bf16x8*)(aLds + (size_t)f * 512 + l * 8) = pk;
    }
    __syncthreads();

    f32x4 acc[4][4];
    #pragma unroll
    for (int rf = 0; rf < 4; ++rf)
        #pragma unroll
        for (int i = 0; i < 4; ++i) acc[rf][i] = f32x4{0.f, 0.f, 0.f, 0.f};

    const unsigned short* ab0 = aLds + lane * 8;

    #pragma unroll 1
    for (int it = 0; it < 6; ++it) {
        int ks = it * 4;
        MSTEP(ks,     bA0, bA1, bA2, bA3)
        if (it < 5) LOADB(bA0, bA1, bA2, bA3, ks + 4)
        MSTEP(ks + 1, bB0, bB1, bB2, bB3)
        if (it < 5) LOADB(bB0, bB1, bB2, bB3, ks + 5)
        MSTEP(ks + 2, bC0, bC1, bC2, bC3)
        if (it < 5) LOADB(bC0, bC1, bC2, bC3, ks + 6)
        MSTEP(ks + 3, bD0, bD1, bD2, bD3)
        if (it < 5) LOADB(bD0, bD1, bD2, bD3, ks + 7)
    }

    // epilogue: per-row sum over this wave's 64 cols of gelu(h+b1)*w2
    int col16 = lane & 15, quart = lane >> 4;
    float b1v[4], w2v[4];
    #pragma unroll
    for (int i = 0; i < 4; ++i) {
        int c = cg * 64 + i * 16 + col16;
        b1v[i] = rb1[c]; w2v[i] = rw2[c];
    }
    #pragma unroll
    for (int rf = 0; rf < 4; ++rf) {
        #pragma unroll
        for (int r = 0; r < 4; ++r) {
            float s = 0.f;
            #pragma unroll
            for (int i = 0; i < 4; ++i)
                s += gelu_f(acc[rf][i][r] + b1v[i]) * w2v[i];
            #pragma unroll
            for (int m = 1; m < 16; m <<= 1) s += __shfl_xor(s, m);
            if (col16 == 0) part[wid * 64 + rf * 16 + quart * 4 + r] = s;
        }
    }
    __syncthreads();
    if (tid < 192) {
        int tt = tid >> 6, row = tid & 63;
        float v = part[(tt * 4 + 0) * 64 + row] + part[(tt * 4 + 1) * 64 + row]
                + part[(tt * 4 + 2) * 64 + row] + part[(tt * 4 + 3) * 64 + row] + rb2[0];
        float p = 1.f / (1.f + __expf(-v));
        dprob[(size_t)tt * NUM_EDGES + blk * BM + row] = p;
    }
}

// Kzero: zero raw accumulators e1..e3
__global__ void kzero(float* __restrict__ ws) {
    int i = blockIdx.x * 256 + threadIdx.x;
    if (i < 3 * NUM_ENT) ws[WS_E + NUM_ENT + i] = 0.f;
}

// K9: scatter step t: e_{t+1}[obj] += norm(e_t)[sub] * dprob[t][e]
__global__ void k9_scatter(const int* __restrict__ kb, const int* __restrict__ topics,
                           float* __restrict__ ws, int t) {
    int e = blockIdx.x * 256 + threadIdx.x;
    if (e >= NUM_EDGES) return;
    int sub = kb[2 * e], obj = kb[2 * e + 1];
    float g;
    if (t == 0) {
        g = (sub == topics[0] || sub == topics[1] || sub == topics[2] || sub == topics[3]) ? 1.f : 0.f;
    } else {
        float v = ws[WS_E + (size_t)t * NUM_ENT + sub];
        g = v / fmaxf(v, 1.f);
    }
    float p = g * ws[WS_DPROB + (size_t)t * NUM_EDGES + e];
    if (p != 0.f) atomicAdd(&ws[WS_E + (size_t)(t + 1) * NUM_ENT + obj], p);
}

// Kout: out[i] = sum_t hop_attn[t] * norm(e_{t+1})[i]
__global__ void kout(const float* __restrict__ ws, float* __restrict__ out) {
    int i = blockIdx.x * 256 + threadIdx.x;
    if (i >= NUM_ENT) return;
    float v1 = ws[WS_E + 1 * NUM_ENT + i]; v1 /= fmaxf(v1, 1.f);
    float v2 = ws[WS_E + 2 * NUM_ENT + i]; v2 /= fmaxf(v2, 1.f);
    float v3 = ws[WS_E + 3 * NUM_ENT + i]; v3 /= fmaxf(v3, 1.f);
    out[i] = ws[WS_HA + 0] * v1 + ws[WS_HA + 1] * v2 + ws[WS_HA + 2] * v3;
}

extern "C" void kernel_launch(void* const* d_in, const int* in_sizes, int n_in,
                              void* d_out, int out_size, void* d_ws, size_t ws_size,
                              hipStream_t stream) {
    const float* q_emb   = (const float*)d_in[0];
    const float* qwh     = (const float*)d_in[1];
    const float* desc    = (const float*)d_in[2];
    const float* sw1     = (const float*)d_in[3];
    const float* sb1     = (const float*)d_in[4];
    const float* sw2     = (const float*)d_in[5];
    const float* sb2     = (const float*)d_in[6];
    const float* rw1     = (const float*)d_in[7];
    const float* rb1     = (const float*)d_in[8];
    const float* rw2     = (const float*)d_in[9];
    const float* rb2     = (const float*)d_in[10];
    const float* hw1     = (const float*)d_in[11];
    const float* hb1     = (const float*)d_in[12];
    const float* hw2     = (const float*)d_in[13];
    const float* hb2     = (const float*)d_in[14];
    const int*   kb      = (const int*)d_in[15];
    const int*   topics  = (const int*)d_in[16];
    float* ws  = (float*)d_ws;
    float* out = (float*)d_out;

    int nblk7 = NUM_EDGES / BM;   // 3125, exact

    kzero<<<(3 * NUM_ENT + 255) / 256, 256, 0, stream>>>(ws);
    k1a<<<64, 256, 0, stream>>>(q_emb, sw1, hw1, ws);
    k1b<<<10, 256, 0, stream>>>(sb1, hb1, ws);
    k2a<<<48, 256, 0, stream>>>(sw2, ws);
    k2b<<<9, 256, 0, stream>>>(sb2, ws);
    k345<<<1, 1024, 0, stream>>>(qwh, hw2, hb2, ws);
    k6_bmat<<<288, 256, 0, stream>>>(rw1, ws);
    k7_gemm<<<nblk7, 768, 101376, stream>>>(desc, rb1, rw2, rb2, ws);
    for (int t = 0; t < 3; ++t)
        k9_scatter<<<(NUM_EDGES + 255) / 256, 256, 0, stream>>>(kb, topics, ws, t);
    kout<<<(NUM_ENT + 255) / 256, 256, 0, stream>>>(ws, out);
}